// Round 7
// baseline (379.550 us; speedup 1.0000x reference)
//
#include <hip/hip_runtime.h>
#include <math.h>

#define B_ 32
#define T_ 256
#define H_ 128
#define KL_ 500
#define KS_ 10

// ---------------- K1: convs (+ fused hb) ----------------
// grid (32, 7): blockIdx.y 0..2 = conv_l out-ch, 3..5 = conv_s out-ch, 6 = hb
__global__ void k_front(const float* __restrict__ in1, const float* __restrict__ in2,
                        const float* __restrict__ wl, const float* __restrict__ bl,
                        const float* __restrict__ ws, const float* __restrict__ bs,
                        const float* __restrict__ h, const float* __restrict__ Whh,
                        const float* __restrict__ bh,
                        float* __restrict__ xf, float* __restrict__ hb,
                        float* __restrict__ dout) {
    int b = blockIdx.x, oc = blockIdx.y;
    int t = threadIdx.x;  // 256 threads
    if (oc == 6) {  // hb = h @ Whh.T + bh ; copy h into d_out[32:]
        __shared__ float hrow[128];
        if (t < 128) hrow[t] = h[b * 128 + t];
        __syncthreads();
        if (t < 128) {
            float acc = bh[t];
            #pragma unroll 4
            for (int k = 0; k < 128; ++k) acc += hrow[k] * Whh[t * 128 + k];
            hb[b * 128 + t] = acc;
            dout[32 + b * 128 + t] = hrow[t];
        }
        return;
    }
    __shared__ float s_in[755 * 3];
    __shared__ float s_w[3 * KL_];
    if (oc < 3) {
        int o = oc;
        for (int i = t; i < 755 * 3; i += 256) s_in[i] = in1[b * 755 * 3 + i];
        for (int i = t; i < 3 * KL_; i += 256) s_w[i] = wl[o * 3 * KL_ + i];
        __syncthreads();
        float acc = bl[o];
        for (int i = 0; i < 3; ++i) {
            const float* wrow = &s_w[i * KL_];
            #pragma unroll 4
            for (int k = 0; k < KL_; ++k)
                acc += s_in[(t + k) * 3 + i] * wrow[k];
        }
        xf[(b * T_ + t) * 6 + o] = acc;
    } else {
        int o = oc - 3;
        for (int i = t; i < 265 * 3; i += 256) s_in[i] = in2[b * 265 * 3 + i];
        for (int i = t; i < 3 * KS_; i += 256) s_w[i] = ws[o * 3 * KS_ + i];
        __syncthreads();
        float acc = bs[o];
        for (int i = 0; i < 3; ++i) {
            #pragma unroll
            for (int k = 0; k < KS_; ++k)
                acc += s_in[(t + k) * 3 + i] * s_w[i * KS_ + k];
        }
        xf[(b * T_ + t) * 6 + 3 + o] = acc;
    }
}

// ---------------- K2: features -> lane-permuted tiles ----------------
// rwP[t][j][lane] (float4): lane l=2b+hf, j=(k&63)>>2, c=k&3  (phase-A rows)
// clP[t][j][lane] (float4): lane l=k>>1, j=(b>>2)+8*(k&1), c=b&3 (phase-B cols)
__global__ void k_feat(const float* __restrict__ xf, const float* __restrict__ in3,
                       const float* __restrict__ hb, const float* __restrict__ Wih,
                       const float* __restrict__ tk, const float* __restrict__ tv,
                       const float* __restrict__ tq,
                       float* __restrict__ rwP, float* __restrict__ clP,
                       float* __restrict__ lblT, float* __restrict__ outq) {
    int t = blockIdx.x;
    int tid = threadIdx.x;
    __shared__ float out_s[B_ * H_];
    __shared__ __align__(16) float tkc[16 * H_];
    __shared__ __align__(16) float tvc[16 * H_];
    __shared__ __align__(16) float tqc[16 * H_];

    for (int o = 0; o < 16; ++o) {
        int idx = o * 256 + tid;
        int b = idx >> 7, hh = idx & 127;
        const float* w = &Wih[hh * 9];
        const float* x6 = &xf[(b * T_ + t) * 6];
        const float* x3 = &in3[(b * T_ + t) * 3];
        float acc = hb[idx];
        acc += x6[0] * w[0] + x6[1] * w[1] + x6[2] * w[2]
             + x6[3] * w[3] + x6[4] * w[4] + x6[5] * w[5]
             + x3[0] * w[6] + x3[1] * w[7] + x3[2] * w[8];
        out_s[idx] = acc;
    }
    __syncthreads();

    float a_tr[16], a_lb[16], a_tq[16];
    #pragma unroll
    for (int o = 0; o < 16; ++o) { a_tr[o] = 0.f; a_lb[o] = 0.f; a_tq[o] = 0.f; }
    const bool last = (t == T_ - 1);

    for (int kc = 0; kc < 8; ++kc) {
        __syncthreads();
        {
            const float4* s1 = (const float4*)(tk + kc * 2048);
            const float4* s2 = (const float4*)(tv + kc * 2048);
            float4* d1 = (float4*)tkc;
            float4* d2 = (float4*)tvc;
            d1[tid * 2]     = s1[tid * 2];
            d1[tid * 2 + 1] = s1[tid * 2 + 1];
            d2[tid * 2]     = s2[tid * 2];
            d2[tid * 2 + 1] = s2[tid * 2 + 1];
            if (last) {
                const float4* s3 = (const float4*)(tq + kc * 2048);
                float4* d3 = (float4*)tqc;
                d3[tid * 2]     = s3[tid * 2];
                d3[tid * 2 + 1] = s3[tid * 2 + 1];
            }
        }
        __syncthreads();
        for (int o = 0; o < 16; ++o) {
            int idx = o * 256 + tid;
            int b = idx >> 7, hh = idx & 127;
            const float* os = &out_s[b * 128 + kc * 16];
            #pragma unroll
            for (int k2 = 0; k2 < 16; ++k2) {
                float ov = os[k2];
                a_tr[o] += ov * tkc[k2 * 128 + hh];
                a_lb[o] += ov * tvc[k2 * 128 + hh];
                if (last) a_tq[o] += ov * tqc[k2 * 128 + hh];
            }
        }
    }
    for (int o = 0; o < 16; ++o) {
        int idx = o * 256 + tid;
        int b = idx >> 7, hh = idx & 127;  // value = trv[t][b][hh]
        rwP[t * 4096 + (((hh & 63) >> 2) << 8) + ((2 * b + (hh >> 6)) << 2) + (hh & 3)] = a_tr[o];
        clP[t * 4096 + (((b >> 2) + 8 * (hh & 1)) << 8) + ((hh >> 1) << 2) + (b & 3)] = a_tr[o];
        lblT[t * 4096 + hh * 32 + b] = a_lb[o];
        if (last) outq[idx] = a_tq[o];
    }
}

// ---------------- K3: Adam scan — 1 wave/row, reg-resident w, depth-2 prefetch ----------------
// per-step critical chain: phaseA(reg FMAs) -> g -> readlanes -> phaseB -> Adam(w)
// -> ds_write -> 16 ds_read (prefetched into wreg for NEXT step, overlapping
// bias-Adam + t+2 tile prefetch + backedge). All bias-correct factors folded
// into one uniform scalar na; 1/(sqrt(v)+eps) -> rsqrt(v+1e-16) (rel err ~2e-6).
#define DPP_ADD(S, CTRL)                                                           \
  do { int _d = __builtin_amdgcn_update_dpp(0, __float_as_int(S), (CTRL), 0xF,     \
                                            0xF, true);                            \
       (S) += __int_as_float(_d); } while (0)

#define SCAN_STEP(RW, CL, LB, TT)                                                  \
  do {                                                                             \
    pb1 *= BB1; pb2 *= BB2;                                                        \
    const float na = (-lr) * __builtin_amdgcn_sqrtf(1.0f - pb2) *                  \
                     __builtin_amdgcn_rcpf(1.0f - pb1);                            \
    const float cgbml = cg * (bm - (LB));                                          \
    /* phase A: pred partial, w from registers (wreg) */                           \
    float a0 = 0.f, a1 = 0.f, a2 = 0.f, a3 = 0.f;                                  \
    float a4 = 0.f, a5 = 0.f, a6 = 0.f, a7 = 0.f;                                  \
    _Pragma("unroll")                                                              \
    for (int j = 0; j < 8; ++j) {                                                  \
      float4 xv = RW[j], wv4 = wreg[j];                                            \
      a0 = fmaf(xv.x, wv4.x, a0); a1 = fmaf(xv.y, wv4.y, a1);                      \
      a2 = fmaf(xv.z, wv4.z, a2); a3 = fmaf(xv.w, wv4.w, a3);                      \
    }                                                                              \
    _Pragma("unroll")                                                              \
    for (int j = 8; j < 16; ++j) {                                                 \
      float4 xv = RW[j], wv4 = wreg[j];                                            \
      a4 = fmaf(xv.x, wv4.x, a4); a5 = fmaf(xv.y, wv4.y, a5);                      \
      a6 = fmaf(xv.z, wv4.z, a6); a7 = fmaf(xv.w, wv4.w, a7);                      \
    }                                                                              \
    float pp = ((a0 + a2) + (a1 + a3)) + ((a4 + a6) + (a5 + a7));                  \
    int po = __builtin_amdgcn_update_dpp(0, __float_as_int(pp), 0xB1, 0xF, 0xF,    \
                                         true);                                    \
    float pred = pp + __int_as_float(po);                                          \
    float g = fmaf(cg, pred, cgbml);                                               \
    /* prefetch rows + lbl for TT+2 */                                             \
    {                                                                              \
      const int tpre = ((TT) + 2 < 256) ? ((TT) + 2) : 255;                        \
      const float4* rs = (const float4*)(rwP + (size_t)tpre * 4096);               \
      _Pragma("unroll")                                                            \
      for (int j = 0; j < 16; ++j) RW[j] = rs[j * 64 + lane];                      \
      LB = lblT[(size_t)tpre * 4096 + lblidx];                                     \
    }                                                                              \
    /* bias grad: butterfly sum of the 32 distinct g's (pair-replicated lanes) */  \
    float gsum = g;                                                                \
    DPP_ADD(gsum, 0x4E);   /* quad_perm xor2 */                                    \
    DPP_ADD(gsum, 0x124);  /* row_ror:4 */                                         \
    DPP_ADD(gsum, 0x128);  /* row_ror:8 */                                         \
    gsum += __shfl_xor(gsum, 16);                                                  \
    gsum += __shfl_xor(gsum, 32);                                                  \
    /* g broadcast: 32 readlanes into scalar regs */                               \
    float ga[32];                                                                  \
    _Pragma("unroll")                                                              \
    for (int b = 0; b < 32; ++b)                                                   \
      ga[b] = __int_as_float(                                                      \
          __builtin_amdgcn_readlane(__float_as_int(g), 2 * b));                    \
    /* phase B: gW for this lane's two columns (register-local) */                 \
    float e00 = 0.f, e01 = 0.f, e02 = 0.f, e03 = 0.f;                              \
    float e10 = 0.f, e11 = 0.f, e12 = 0.f, e13 = 0.f;                              \
    _Pragma("unroll")                                                              \
    for (int q = 0; q < 8; ++q) {                                                  \
      float4 c0 = CL[q];                                                           \
      float4 c1 = CL[8 + q];                                                       \
      e00 = fmaf(ga[4 * q + 0], c0.x, e00); e01 = fmaf(ga[4 * q + 1], c0.y, e01);  \
      e02 = fmaf(ga[4 * q + 2], c0.z, e02); e03 = fmaf(ga[4 * q + 3], c0.w, e03);  \
      e10 = fmaf(ga[4 * q + 0], c1.x, e10); e11 = fmaf(ga[4 * q + 1], c1.y, e11);  \
      e12 = fmaf(ga[4 * q + 2], c1.z, e12); e13 = fmaf(ga[4 * q + 3], c1.w, e13);  \
    }                                                                              \
    const float gk0 = (e00 + e02) + (e01 + e03);                                   \
    const float gk1 = (e10 + e12) + (e11 + e13);                                   \
    /* prefetch cols for TT+2 */                                                   \
    {                                                                              \
      const int tpre = ((TT) + 2 < 256) ? ((TT) + 2) : 255;                        \
      const float4* cs = (const float4*)(clP + (size_t)tpre * 4096);               \
      _Pragma("unroll")                                                            \
      for (int j = 0; j < 16; ++j) CL[j] = cs[j * 64 + lane];                      \
    }                                                                              \
    /* Adam W (folded bias-correction, rsqrt) */                                   \
    {                                                                              \
      float t0 = OB1 * gk0; mW0 = fmaf(BB1, mW0, t0);                              \
      float t1 = gk0 * gk0; float t2 = OB2 * t1; vW0 = fmaf(BB2, vW0, t2);         \
      float r0 = __builtin_amdgcn_rsqf(vW0 + SEPS);                                \
      w0 = fmaf(mW0 * r0, na, w0);                                                 \
      float t3 = OB1 * gk1; mW1 = fmaf(BB1, mW1, t3);                              \
      float t4 = gk1 * gk1; float t5 = OB2 * t4; vW1 = fmaf(BB2, vW1, t5);         \
      float r1 = __builtin_amdgcn_rsqf(vW1 + SEPS);                                \
      w1 = fmaf(mW1 * r1, na, w1);                                                 \
    }                                                                              \
    *(float2*)&w_s[2 * lane] = make_float2(w0, w1);                                \
    /* prefetch NEXT step's w into registers (reads follow write in DS order) */   \
    _Pragma("unroll")                                                              \
    for (int j = 0; j < 16; ++j) wreg[j] = *(const float4*)&w_s[hf64 + 4 * j];     \
    /* bias Adam (redundant all lanes, off critical path) */                       \
    {                                                                              \
      float t6 = OB1 * gsum; mb = fmaf(BB1, mb, t6);                               \
      float t7 = gsum * gsum; float t8 = OB2 * t7; vb = fmaf(BB2, vb, t8);         \
      float rb = __builtin_amdgcn_rsqf(vb + SEPS);                                 \
      bm = fmaf(mb * rb, na, bm);                                                  \
    }                                                                              \
  } while (0)

__global__
__attribute__((amdgpu_flat_work_group_size(64, 64), amdgpu_waves_per_eu(1, 1)))
void k_scan(
    const float* __restrict__ rwP, const float* __restrict__ clP,
    const float* __restrict__ lblT,
    const float* __restrict__ Wm0, const float* __restrict__ bm0,
    const float* __restrict__ outq, float* __restrict__ hi_ws) {
    const int h = blockIdx.x;
    const int lane = threadIdx.x;            // 0..63
    const int row = lane >> 1;
    const int hf = lane & 1;
    const int hf64 = hf * 64;
    const int rowbase = row * 128 + hf64;    // for outq epilogue only
    const int lblidx = h * 32 + row;

    __shared__ __align__(16) float w_s[H_];

    // Adam state: this lane owns Wm[h][2*lane], Wm[h][2*lane+1]
    float2 wv = *(const float2*)&Wm0[h * 128 + 2 * lane];
    float w0 = wv.x, w1 = wv.y;
    float mW0 = 0.f, vW0 = 0.f, mW1 = 0.f, vW1 = 0.f;
    float bm = bm0[h];
    float mb = 0.f, vb = 0.f, pb1 = 1.f, pb2 = 1.f;

    *(float2*)&w_s[2 * lane] = wv;

    float4 wreg[16];
    #pragma unroll
    for (int j = 0; j < 16; ++j) wreg[j] = *(const float4*)&w_s[hf64 + 4 * j];

    // depth-2 pipeline: set A = even t, set B = odd t
    float4 rwA[16], rwB[16], clA[16], clB[16];
    float lA, lB;
    {
        const float4* r0 = (const float4*)(rwP);
        const float4* c0 = (const float4*)(clP);
        const float4* r1 = (const float4*)(rwP + 4096);
        const float4* c1 = (const float4*)(clP + 4096);
        #pragma unroll
        for (int j = 0; j < 16; ++j) rwA[j] = r0[j * 64 + lane];
        #pragma unroll
        for (int j = 0; j < 16; ++j) clA[j] = c0[j * 64 + lane];
        lA = lblT[lblidx];
        #pragma unroll
        for (int j = 0; j < 16; ++j) rwB[j] = r1[j * 64 + lane];
        #pragma unroll
        for (int j = 0; j < 16; ++j) clB[j] = c1[j * 64 + lane];
        lB = lblT[4096 + lblidx];
    }

    const float cg = 2.0f / 4096.0f;
    const float lr = 0.01f, BB1 = 0.9f, BB2 = 0.999f;
    const float OB1 = 0.1f, OB2 = 0.001f;
    const float SEPS = 1e-16f;

    for (int t = 0; t < T_; t += 2) {
        SCAN_STEP(rwA, clA, lA, t);
        SCAN_STEP(rwB, clB, lB, t + 1);
    }

    // ---- epilogue: hi[:,h] = outq @ Wm_final[h,:] + bm_final (w in wreg) ----
    {
        const float4* es = (const float4*)(outq + rowbase);
        float ax = 0.f, ay = 0.f, az = 0.f, aw = 0.f;
        #pragma unroll
        for (int j = 0; j < 16; ++j) {
            float4 xv = es[j];
            float4 wv4 = wreg[j];
            ax = fmaf(xv.x, wv4.x, ax); ay = fmaf(xv.y, wv4.y, ay);
            az = fmaf(xv.z, wv4.z, az); aw = fmaf(xv.w, wv4.w, aw);
        }
        float pp = (ax + az) + (ay + aw);
        int po = __builtin_amdgcn_update_dpp(0, __float_as_int(pp), 0xB1, 0xF, 0xF, true);
        float pred = pp + __int_as_float(po);
        if (hf == 0) hi_ws[row * 128 + h] = pred + bm;
    }
}

// ---------------- K4: y = hi@W_ho.T + b_o ; out = y@out_W.T + out_b ----------------
__global__ void k_out(const float* __restrict__ hi, const float* __restrict__ Who,
                      const float* __restrict__ bo, const float* __restrict__ outW,
                      const float* __restrict__ outb, float* __restrict__ dout) {
    int b = blockIdx.x, hh = threadIdx.x;  // 32 blocks x 128 threads
    __shared__ float hrow[128];
    __shared__ float part[2];
    hrow[hh] = hi[b * 128 + hh];
    __syncthreads();
    float acc = bo[hh];
    #pragma unroll 4
    for (int k = 0; k < 128; ++k) acc += hrow[k] * Who[hh * 128 + k];
    float v = acc * outW[hh];
    v += __shfl_down(v, 32, 64);
    v += __shfl_down(v, 16, 64);
    v += __shfl_down(v, 8, 64);
    v += __shfl_down(v, 4, 64);
    v += __shfl_down(v, 2, 64);
    v += __shfl_down(v, 1, 64);
    if ((hh & 63) == 0) part[hh >> 6] = v;
    __syncthreads();
    if (hh == 0) dout[b] = part[0] + part[1] + outb[0];
}

extern "C" void kernel_launch(void* const* d_in, const int* in_sizes, int n_in,
                              void* d_out, int out_size, void* d_ws, size_t ws_size,
                              hipStream_t stream) {
    (void)in_sizes; (void)n_in; (void)out_size; (void)ws_size;
    const float* in1   = (const float*)d_in[0];   // [32,755,3]
    const float* in2   = (const float*)d_in[1];   // [32,265,3]
    const float* in3   = (const float*)d_in[2];   // [32,256,3]
    const float* h     = (const float*)d_in[3];   // [32,128]
    const float* Wih   = (const float*)d_in[4];   // [128,9]
    const float* Whh   = (const float*)d_in[5];   // [128,128]
    const float* bh    = (const float*)d_in[6];   // [128]
    const float* Who   = (const float*)d_in[7];   // [128,128]
    const float* bo    = (const float*)d_in[8];   // [128]
    const float* wl    = (const float*)d_in[9];   // [3,3,500]
    const float* bl    = (const float*)d_in[10];  // [3]
    const float* wsc   = (const float*)d_in[11];  // [3,3,10]
    const float* bsc   = (const float*)d_in[12];  // [3]
    const float* tk    = (const float*)d_in[13];  // [1,128,128]
    const float* tv    = (const float*)d_in[14];
    const float* tq    = (const float*)d_in[15];
    const float* Wm0   = (const float*)d_in[16];  // [128,128]
    const float* bm0   = (const float*)d_in[17];  // [128]
    const float* outW  = (const float*)d_in[18];  // [1,128]
    const float* outb  = (const float*)d_in[19];  // [1]
    float* out = (float*)d_out;

    float* wsf = (float*)d_ws;
    float* xf    = wsf;                       // 49152
    float* hb    = wsf + 49152;               // 4096
    float* rwP   = wsf + 53248;               // 1048576
    float* clP   = wsf + 53248 + 1048576;     // 1048576
    float* lblT  = wsf + 53248 + 2097152;     // 1048576
    float* outq  = wsf + 53248 + 3145728;     // 4096
    float* hi_ws = wsf + 53248 + 3149824;     // 4096

    k_front<<<dim3(32, 7), 256, 0, stream>>>(in1, in2, wl, bl, wsc, bsc,
                                             h, Whh, bh, xf, hb, out);
    k_feat<<<256, 256, 0, stream>>>(xf, in3, hb, Wih, tk, tv, tq,
                                    rwP, clP, lblT, outq);
    k_scan<<<128, 64, 0, stream>>>(rwP, clP, lblT, Wm0, bm0, outq, hi_ws);
    k_out<<<32, 128, 0, stream>>>(hi_ws, Who, bo, outW, outb, out);
}

// Round 8
// 375.131 us; speedup vs baseline: 1.0118x; 1.0118x over previous
//
#include <hip/hip_runtime.h>
#include <math.h>

#define B_ 32
#define T_ 256
#define H_ 128
#define KL_ 500
#define KS_ 10

typedef _Float16 h8 __attribute__((ext_vector_type(8)));  // 16B = 8 fp16

// ---------------- K1: convs (+ fused hb) ----------------
// grid (32, 7): blockIdx.y 0..2 = conv_l out-ch, 3..5 = conv_s out-ch, 6 = hb
__global__ void k_front(const float* __restrict__ in1, const float* __restrict__ in2,
                        const float* __restrict__ wl, const float* __restrict__ bl,
                        const float* __restrict__ ws, const float* __restrict__ bs,
                        const float* __restrict__ h, const float* __restrict__ Whh,
                        const float* __restrict__ bh,
                        float* __restrict__ xf, float* __restrict__ hb,
                        float* __restrict__ dout) {
    int b = blockIdx.x, oc = blockIdx.y;
    int t = threadIdx.x;  // 256 threads
    if (oc == 6) {  // hb = h @ Whh.T + bh ; copy h into d_out[32:]
        __shared__ float hrow[128];
        if (t < 128) hrow[t] = h[b * 128 + t];
        __syncthreads();
        if (t < 128) {
            float acc = bh[t];
            #pragma unroll 4
            for (int k = 0; k < 128; ++k) acc += hrow[k] * Whh[t * 128 + k];
            hb[b * 128 + t] = acc;
            dout[32 + b * 128 + t] = hrow[t];
        }
        return;
    }
    __shared__ float s_in[755 * 3];
    __shared__ float s_w[3 * KL_];
    if (oc < 3) {
        int o = oc;
        for (int i = t; i < 755 * 3; i += 256) s_in[i] = in1[b * 755 * 3 + i];
        for (int i = t; i < 3 * KL_; i += 256) s_w[i] = wl[o * 3 * KL_ + i];
        __syncthreads();
        float acc = bl[o];
        for (int i = 0; i < 3; ++i) {
            const float* wrow = &s_w[i * KL_];
            #pragma unroll 4
            for (int k = 0; k < KL_; ++k)
                acc += s_in[(t + k) * 3 + i] * wrow[k];
        }
        xf[(b * T_ + t) * 6 + o] = acc;
    } else {
        int o = oc - 3;
        for (int i = t; i < 265 * 3; i += 256) s_in[i] = in2[b * 265 * 3 + i];
        for (int i = t; i < 3 * KS_; i += 256) s_w[i] = ws[o * 3 * KS_ + i];
        __syncthreads();
        float acc = bs[o];
        for (int i = 0; i < 3; ++i) {
            #pragma unroll
            for (int k = 0; k < KS_; ++k)
                acc += s_in[(t + k) * 3 + i] * s_w[i * KS_ + k];
        }
        xf[(b * T_ + t) * 6 + 3 + o] = acc;
    }
}

// ---------------- K2: features -> lane-permuted fp16 tiles ----------------
// rwP (fp16): lane l=2b+(hh>>6), p=hh&63:  off = t*4096 + (p>>3)*512 + l*8 + (p&7)
// clP (fp16): lane l=hh>>1, q=(hh&1)*32+b: off = t*4096 + (q>>3)*512 + l*8 + (q&7)
// k_scan load j reads 16B at t*8KB + j*1024B + lane*16B — coalesced.
__global__ void k_feat(const float* __restrict__ xf, const float* __restrict__ in3,
                       const float* __restrict__ hb, const float* __restrict__ Wih,
                       const float* __restrict__ tk, const float* __restrict__ tv,
                       const float* __restrict__ tq,
                       _Float16* __restrict__ rwP, _Float16* __restrict__ clP,
                       float* __restrict__ lblT, float* __restrict__ outq) {
    int t = blockIdx.x;
    int tid = threadIdx.x;
    __shared__ float out_s[B_ * H_];
    __shared__ __align__(16) float tkc[16 * H_];
    __shared__ __align__(16) float tvc[16 * H_];
    __shared__ __align__(16) float tqc[16 * H_];

    for (int o = 0; o < 16; ++o) {
        int idx = o * 256 + tid;
        int b = idx >> 7, hh = idx & 127;
        const float* w = &Wih[hh * 9];
        const float* x6 = &xf[(b * T_ + t) * 6];
        const float* x3 = &in3[(b * T_ + t) * 3];
        float acc = hb[idx];
        acc += x6[0] * w[0] + x6[1] * w[1] + x6[2] * w[2]
             + x6[3] * w[3] + x6[4] * w[4] + x6[5] * w[5]
             + x3[0] * w[6] + x3[1] * w[7] + x3[2] * w[8];
        out_s[idx] = acc;
    }
    __syncthreads();

    float a_tr[16], a_lb[16], a_tq[16];
    #pragma unroll
    for (int o = 0; o < 16; ++o) { a_tr[o] = 0.f; a_lb[o] = 0.f; a_tq[o] = 0.f; }
    const bool last = (t == T_ - 1);

    for (int kc = 0; kc < 8; ++kc) {
        __syncthreads();
        {
            const float4* s1 = (const float4*)(tk + kc * 2048);
            const float4* s2 = (const float4*)(tv + kc * 2048);
            float4* d1 = (float4*)tkc;
            float4* d2 = (float4*)tvc;
            d1[tid * 2]     = s1[tid * 2];
            d1[tid * 2 + 1] = s1[tid * 2 + 1];
            d2[tid * 2]     = s2[tid * 2];
            d2[tid * 2 + 1] = s2[tid * 2 + 1];
            if (last) {
                const float4* s3 = (const float4*)(tq + kc * 2048);
                float4* d3 = (float4*)tqc;
                d3[tid * 2]     = s3[tid * 2];
                d3[tid * 2 + 1] = s3[tid * 2 + 1];
            }
        }
        __syncthreads();
        for (int o = 0; o < 16; ++o) {
            int idx = o * 256 + tid;
            int b = idx >> 7, hh = idx & 127;
            const float* os = &out_s[b * 128 + kc * 16];
            #pragma unroll
            for (int k2 = 0; k2 < 16; ++k2) {
                float ov = os[k2];
                a_tr[o] += ov * tkc[k2 * 128 + hh];
                a_lb[o] += ov * tvc[k2 * 128 + hh];
                if (last) a_tq[o] += ov * tqc[k2 * 128 + hh];
            }
        }
    }
    for (int o = 0; o < 16; ++o) {
        int idx = o * 256 + tid;
        int b = idx >> 7, hh = idx & 127;  // value = trv[t][b][hh]
        _Float16 v16 = (_Float16)a_tr[o];
        int p = hh & 63;
        rwP[t * 4096 + ((p >> 3) << 9) + ((2 * b + (hh >> 6)) << 3) + (p & 7)] = v16;
        int q = ((hh & 1) << 5) + b;
        clP[t * 4096 + ((q >> 3) << 9) + ((hh >> 1) << 3) + (q & 7)] = v16;
        lblT[t * 4096 + hh * 32 + b] = a_lb[o];
        if (last) outq[idx] = a_tq[o];
    }
}

// ---------------- K3: Adam scan — 1 wave/row, fp16 tiles, depth-2 prefetch ----------------
#define DPP_ADD(S, CTRL)                                                           \
  do { int _d = __builtin_amdgcn_update_dpp(0, __float_as_int(S), (CTRL), 0xF,     \
                                            0xF, true);                            \
       (S) += __int_as_float(_d); } while (0)

#define PHASEA_J(j, RW)                                                            \
  { h8 xv = RW[j]; float4 wa = wreg[2 * (j)], wb = wreg[2 * (j) + 1];              \
    a0 = fmaf((float)xv[0], wa.x, a0); a1 = fmaf((float)xv[1], wa.y, a1);          \
    a2 = fmaf((float)xv[2], wa.z, a2); a3 = fmaf((float)xv[3], wa.w, a3);          \
    a4 = fmaf((float)xv[4], wb.x, a4); a5 = fmaf((float)xv[5], wb.y, a5);          \
    a6 = fmaf((float)xv[6], wb.z, a6); a7 = fmaf((float)xv[7], wb.w, a7); }

#define PHASEB0_J(j, CL)                                                           \
  { h8 cv = CL[j];                                                                 \
    f0 = fmaf(ga[8 * (j) + 0], (float)cv[0], f0);                                  \
    f1 = fmaf(ga[8 * (j) + 1], (float)cv[1], f1);                                  \
    f2 = fmaf(ga[8 * (j) + 2], (float)cv[2], f2);                                  \
    f3 = fmaf(ga[8 * (j) + 3], (float)cv[3], f3);                                  \
    f0 = fmaf(ga[8 * (j) + 4], (float)cv[4], f0);                                  \
    f1 = fmaf(ga[8 * (j) + 5], (float)cv[5], f1);                                  \
    f2 = fmaf(ga[8 * (j) + 6], (float)cv[6], f2);                                  \
    f3 = fmaf(ga[8 * (j) + 7], (float)cv[7], f3); }

#define PHASEB1_J(j, CL)                                                           \
  { h8 cv = CL[(j) + 4];                                                           \
    f4 = fmaf(ga[8 * (j) + 0], (float)cv[0], f4);                                  \
    f5 = fmaf(ga[8 * (j) + 1], (float)cv[1], f5);                                  \
    f6 = fmaf(ga[8 * (j) + 2], (float)cv[2], f6);                                  \
    f7 = fmaf(ga[8 * (j) + 3], (float)cv[3], f7);                                  \
    f4 = fmaf(ga[8 * (j) + 4], (float)cv[4], f4);                                  \
    f5 = fmaf(ga[8 * (j) + 5], (float)cv[5], f5);                                  \
    f6 = fmaf(ga[8 * (j) + 6], (float)cv[6], f6);                                  \
    f7 = fmaf(ga[8 * (j) + 7], (float)cv[7], f7); }

#define SCAN_STEP(RW, CL, LB, TT)                                                  \
  do {                                                                             \
    pb1 *= BB1; pb2 *= BB2;                                                        \
    const float na = (-lr) * __builtin_amdgcn_sqrtf(1.0f - pb2) *                  \
                     __builtin_amdgcn_rcpf(1.0f - pb1);                            \
    const float cgbml = cg * (bm - (LB));                                          \
    /* phase A: pred partial, w from registers (wreg), x from fp16 regs */         \
    float a0 = 0.f, a1 = 0.f, a2 = 0.f, a3 = 0.f;                                  \
    float a4 = 0.f, a5 = 0.f, a6 = 0.f, a7 = 0.f;                                  \
    PHASEA_J(0, RW) PHASEA_J(1, RW) PHASEA_J(2, RW) PHASEA_J(3, RW)                \
    PHASEA_J(4, RW) PHASEA_J(5, RW) PHASEA_J(6, RW) PHASEA_J(7, RW)                \
    float pp = ((a0 + a2) + (a1 + a3)) + ((a4 + a6) + (a5 + a7));                  \
    int po = __builtin_amdgcn_update_dpp(0, __float_as_int(pp), 0xB1, 0xF, 0xF,    \
                                         true);                                    \
    float pred = pp + __int_as_float(po);                                          \
    float g = fmaf(cg, pred, cgbml);                                               \
    /* prefetch rows + lbl for TT+2 */                                             \
    {                                                                              \
      const int tpre = ((TT) + 2 < 256) ? ((TT) + 2) : 255;                        \
      const h8* rs = (const h8*)(rwP + (size_t)tpre * 4096);                       \
      _Pragma("unroll")                                                            \
      for (int j = 0; j < 8; ++j) RW[j] = rs[j * 64 + lane];                       \
      LB = lblT[(size_t)tpre * 4096 + lblidx];                                     \
    }                                                                              \
    /* bias grad: butterfly sum of the 32 distinct g's (pair-replicated lanes) */  \
    float gsum = g;                                                                \
    DPP_ADD(gsum, 0x4E);   /* quad_perm xor2 */                                    \
    DPP_ADD(gsum, 0x124);  /* row_ror:4 */                                         \
    DPP_ADD(gsum, 0x128);  /* row_ror:8 */                                         \
    gsum += __shfl_xor(gsum, 16);                                                  \
    gsum += __shfl_xor(gsum, 32);                                                  \
    /* g broadcast: 32 readlanes into scalar regs */                               \
    float ga[32];                                                                  \
    _Pragma("unroll")                                                              \
    for (int b = 0; b < 32; ++b)                                                   \
      ga[b] = __int_as_float(                                                      \
          __builtin_amdgcn_readlane(__float_as_int(g), 2 * b));                    \
    /* phase B: gW for this lane's two columns (register-local, fp16 tiles) */     \
    float f0 = 0.f, f1 = 0.f, f2 = 0.f, f3 = 0.f;                                  \
    float f4 = 0.f, f5 = 0.f, f6 = 0.f, f7 = 0.f;                                  \
    PHASEB0_J(0, CL) PHASEB0_J(1, CL) PHASEB0_J(2, CL) PHASEB0_J(3, CL)            \
    PHASEB1_J(0, CL) PHASEB1_J(1, CL) PHASEB1_J(2, CL) PHASEB1_J(3, CL)            \
    const float gk0 = (f0 + f2) + (f1 + f3);                                       \
    const float gk1 = (f4 + f6) + (f5 + f7);                                       \
    /* prefetch cols for TT+2 */                                                   \
    {                                                                              \
      const int tpre = ((TT) + 2 < 256) ? ((TT) + 2) : 255;                        \
      const h8* cs = (const h8*)(clP + (size_t)tpre * 4096);                       \
      _Pragma("unroll")                                                            \
      for (int j = 0; j < 8; ++j) CL[j] = cs[j * 64 + lane];                       \
    }                                                                              \
    /* Adam W (folded bias-correction, rsqrt) */                                   \
    {                                                                              \
      float t0 = OB1 * gk0; mW0 = fmaf(BB1, mW0, t0);                              \
      float t1 = gk0 * gk0; float t2 = OB2 * t1; vW0 = fmaf(BB2, vW0, t2);         \
      float r0 = __builtin_amdgcn_rsqf(vW0 + SEPS);                                \
      w0 = fmaf(mW0 * r0, na, w0);                                                 \
      float t3 = OB1 * gk1; mW1 = fmaf(BB1, mW1, t3);                              \
      float t4 = gk1 * gk1; float t5 = OB2 * t4; vW1 = fmaf(BB2, vW1, t5);         \
      float r1 = __builtin_amdgcn_rsqf(vW1 + SEPS);                                \
      w1 = fmaf(mW1 * r1, na, w1);                                                 \
    }                                                                              \
    *(float2*)&w_s[2 * lane] = make_float2(w0, w1);                                \
    /* prefetch NEXT step's w into registers (reads follow write in DS order) */   \
    _Pragma("unroll")                                                              \
    for (int j = 0; j < 16; ++j) wreg[j] = *(const float4*)&w_s[hf64 + 4 * j];     \
    /* bias Adam (redundant all lanes, off critical path) */                       \
    {                                                                              \
      float t6 = OB1 * gsum; mb = fmaf(BB1, mb, t6);                               \
      float t7 = gsum * gsum; float t8 = OB2 * t7; vb = fmaf(BB2, vb, t8);         \
      float rb = __builtin_amdgcn_rsqf(vb + SEPS);                                 \
      bm = fmaf(mb * rb, na, bm);                                                  \
    }                                                                              \
  } while (0)

__global__
__attribute__((amdgpu_flat_work_group_size(64, 64), amdgpu_waves_per_eu(1, 1)))
void k_scan(
    const _Float16* __restrict__ rwP, const _Float16* __restrict__ clP,
    const float* __restrict__ lblT,
    const float* __restrict__ Wm0, const float* __restrict__ bm0,
    const float* __restrict__ outq, float* __restrict__ hi_ws) {
    const int h = blockIdx.x;
    const int lane = threadIdx.x;            // 0..63
    const int row = lane >> 1;
    const int hf = lane & 1;
    const int hf64 = hf * 64;
    const int rowbase = row * 128 + hf64;    // for outq epilogue only
    const int lblidx = h * 32 + row;

    __shared__ __align__(16) float w_s[H_];

    // Adam state: this lane owns Wm[h][2*lane], Wm[h][2*lane+1]
    float2 wv = *(const float2*)&Wm0[h * 128 + 2 * lane];
    float w0 = wv.x, w1 = wv.y;
    float mW0 = 0.f, vW0 = 0.f, mW1 = 0.f, vW1 = 0.f;
    float bm = bm0[h];
    float mb = 0.f, vb = 0.f, pb1 = 1.f, pb2 = 1.f;

    *(float2*)&w_s[2 * lane] = wv;

    float4 wreg[16];
    #pragma unroll
    for (int j = 0; j < 16; ++j) wreg[j] = *(const float4*)&w_s[hf64 + 4 * j];

    // depth-2 pipeline: set A = even t, set B = odd t
    h8 rwA[8], rwB[8], clA[8], clB[8];
    float lA, lB;
    {
        const h8* r0 = (const h8*)(rwP);
        const h8* c0 = (const h8*)(clP);
        const h8* r1 = (const h8*)(rwP + 4096);
        const h8* c1 = (const h8*)(clP + 4096);
        #pragma unroll
        for (int j = 0; j < 8; ++j) rwA[j] = r0[j * 64 + lane];
        #pragma unroll
        for (int j = 0; j < 8; ++j) clA[j] = c0[j * 64 + lane];
        lA = lblT[lblidx];
        #pragma unroll
        for (int j = 0; j < 8; ++j) rwB[j] = r1[j * 64 + lane];
        #pragma unroll
        for (int j = 0; j < 8; ++j) clB[j] = c1[j * 64 + lane];
        lB = lblT[4096 + lblidx];
    }

    const float cg = 2.0f / 4096.0f;
    const float lr = 0.01f, BB1 = 0.9f, BB2 = 0.999f;
    const float OB1 = 0.1f, OB2 = 0.001f;
    const float SEPS = 1e-16f;

    for (int t = 0; t < T_; t += 2) {
        SCAN_STEP(rwA, clA, lA, t);
        SCAN_STEP(rwB, clB, lB, t + 1);
    }

    // ---- epilogue: hi[:,h] = outq @ Wm_final[h,:] + bm_final (w in wreg) ----
    {
        const float4* es = (const float4*)(outq + rowbase);
        float ax = 0.f, ay = 0.f, az = 0.f, aw = 0.f;
        #pragma unroll
        for (int j = 0; j < 16; ++j) {
            float4 xv = es[j];
            float4 wv4 = wreg[j];
            ax = fmaf(xv.x, wv4.x, ax); ay = fmaf(xv.y, wv4.y, ay);
            az = fmaf(xv.z, wv4.z, az); aw = fmaf(xv.w, wv4.w, aw);
        }
        float pp = (ax + az) + (ay + aw);
        int po = __builtin_amdgcn_update_dpp(0, __float_as_int(pp), 0xB1, 0xF, 0xF, true);
        float pred = pp + __int_as_float(po);
        if (hf == 0) hi_ws[row * 128 + h] = pred + bm;
    }
}

// ---------------- K4: y = hi@W_ho.T + b_o ; out = y@out_W.T + out_b ----------------
__global__ void k_out(const float* __restrict__ hi, const float* __restrict__ Who,
                      const float* __restrict__ bo, const float* __restrict__ outW,
                      const float* __restrict__ outb, float* __restrict__ dout) {
    int b = blockIdx.x, hh = threadIdx.x;  // 32 blocks x 128 threads
    __shared__ float hrow[128];
    __shared__ float part[2];
    hrow[hh] = hi[b * 128 + hh];
    __syncthreads();
    float acc = bo[hh];
    #pragma unroll 4
    for (int k = 0; k < 128; ++k) acc += hrow[k] * Who[hh * 128 + k];
    float v = acc * outW[hh];
    v += __shfl_down(v, 32, 64);
    v += __shfl_down(v, 16, 64);
    v += __shfl_down(v, 8, 64);
    v += __shfl_down(v, 4, 64);
    v += __shfl_down(v, 2, 64);
    v += __shfl_down(v, 1, 64);
    if ((hh & 63) == 0) part[hh >> 6] = v;
    __syncthreads();
    if (hh == 0) dout[b] = part[0] + part[1] + outb[0];
}

extern "C" void kernel_launch(void* const* d_in, const int* in_sizes, int n_in,
                              void* d_out, int out_size, void* d_ws, size_t ws_size,
                              hipStream_t stream) {
    (void)in_sizes; (void)n_in; (void)out_size; (void)ws_size;
    const float* in1   = (const float*)d_in[0];   // [32,755,3]
    const float* in2   = (const float*)d_in[1];   // [32,265,3]
    const float* in3   = (const float*)d_in[2];   // [32,256,3]
    const float* h     = (const float*)d_in[3];   // [32,128]
    const float* Wih   = (const float*)d_in[4];   // [128,9]
    const float* Whh   = (const float*)d_in[5];   // [128,128]
    const float* bh    = (const float*)d_in[6];   // [128]
    const float* Who   = (const float*)d_in[7];   // [128,128]
    const float* bo    = (const float*)d_in[8];   // [128]
    const float* wl    = (const float*)d_in[9];   // [3,3,500]
    const float* bl    = (const float*)d_in[10];  // [3]
    const float* wsc   = (const float*)d_in[11];  // [3,3,10]
    const float* bsc   = (const float*)d_in[12];  // [3]
    const float* tk    = (const float*)d_in[13];  // [1,128,128]
    const float* tv    = (const float*)d_in[14];
    const float* tq    = (const float*)d_in[15];
    const float* Wm0   = (const float*)d_in[16];  // [128,128]
    const float* bm0   = (const float*)d_in[17];  // [128]
    const float* outW  = (const float*)d_in[18];  // [1,128]
    const float* outb  = (const float*)d_in[19];  // [1]
    float* out = (float*)d_out;

    float* wsf = (float*)d_ws;
    float*    xf    = wsf;                             // 49152 f
    float*    hb    = wsf + 49152;                     // 4096 f
    _Float16* rwH   = (_Float16*)(wsf + 53248);        // 1048576 halfs (= 524288 f)
    _Float16* clH   = (_Float16*)(wsf + 53248 + 524288);   // 1048576 halfs
    float*    lblT  = wsf + 53248 + 1048576;           // 1048576 f
    float*    outq  = wsf + 53248 + 2097152;           // 4096 f
    float*    hi_ws = wsf + 53248 + 2101248;           // 4096 f

    k_front<<<dim3(32, 7), 256, 0, stream>>>(in1, in2, wl, bl, wsc, bsc,
                                             h, Whh, bh, xf, hb, out);
    k_feat<<<256, 256, 0, stream>>>(xf, in3, hb, Wih, tk, tv, tq,
                                    rwH, clH, lblT, outq);
    k_scan<<<128, 64, 0, stream>>>(rwH, clH, lblT, Wm0, bm0, outq, hi_ws);
    k_out<<<32, 128, 0, stream>>>(hi_ws, Who, bo, outW, outb, out);
}